// Round 1
// baseline (1626.075 us; speedup 1.0000x reference)
//
#include <hip/hip_runtime.h>
#include <math.h>

// Problem constants (fixed by setup_inputs)
#define TOKENS 50176   // B*T*H*W = 2*8*56*56
#define NWTOK  98      // window tokens = 2*7*7
#define NWIN   512     // total windows = B * 256
#define C_DIM  256

// Map a window-ordered token index u -> flat (b,t,h,w) index.
// This single map serves BOTH:
//   gather for roll(-1,-3,-3)+window_partition, and
//   scatter for window_reverse+roll(+1,+3,+3).
__device__ __forceinline__ int win_token_to_flat(int u) {
    int g = u / 98;
    int n = u - g * 98;
    int bb  = g >> 8;          // batch
    int rem = g & 255;
    int tb = rem >> 6, hb = (rem >> 3) & 7, wb = rem & 7;
    int dt = n / 49;
    int r2 = n - dt * 49;
    int dh = r2 / 7, dw = r2 - dh * 7;
    int t = tb * 2 + dt, h = hb * 7 + dh, w = wb * 7 + dw;
    int ts = (t + 1) & 7;
    int hs = h + 3; if (hs >= 56) hs -= 56;
    int wsx = w + 3; if (wsx >= 56) wsx -= 56;
    return ((bb * 8 + ts) * 56 + hs) * 56 + wsx;
}

// LayerNorm over C=256, one wave per token, 4 tokens/block.
// GATHER=true: read from permuted source (LN1 + roll + window partition fused).
template<bool GATHER>
__global__ __launch_bounds__(256) void ln_kernel(
        const float* __restrict__ x, const float* __restrict__ w,
        const float* __restrict__ b, float* __restrict__ out) {
    int token = blockIdx.x * 4 + (threadIdx.x >> 6);
    int lane  = threadIdx.x & 63;
    size_t so = GATHER ? (size_t)win_token_to_flat(token) * C_DIM
                       : (size_t)token * C_DIM;
    const float* src = x + so;
    float v[4];
    float sum = 0.f;
#pragma unroll
    for (int j = 0; j < 4; ++j) { v[j] = src[lane + 64 * j]; sum += v[j]; }
#pragma unroll
    for (int o = 32; o > 0; o >>= 1) sum += __shfl_xor(sum, o, 64);
    float mu = sum * (1.f / 256.f);
    float var = 0.f;
#pragma unroll
    for (int j = 0; j < 4; ++j) { float d = v[j] - mu; var += d * d; }
#pragma unroll
    for (int o = 32; o > 0; o >>= 1) var += __shfl_xor(var, o, 64);
    float rstd = rsqrtf(var * (1.f / 256.f) + 1e-5f);
    float* dst = out + (size_t)token * C_DIM;
#pragma unroll
    for (int j = 0; j < 4; ++j) {
        int c = lane + 64 * j;
        dst[c] = (v[j] - mu) * rstd * w[c] + b[c];
    }
}

// Tiled fp32 GEMM: C(MxN) = A(MxK) @ B(NxK)^T [+ bias][+ epilogue]
// BM=BN=64, BK=16, 256 threads, 4x4 accum per thread.
// EPI: 0 = +bias store        (qkv)
//      1 = +bias, scatter via win_token_to_flat, += residual  (proj)
//      2 = +bias, exact GELU  (fc1)
//      3 = +bias, += residual in-place rows  (fc2)
template<int EPI>
__global__ __launch_bounds__(256) void gemm_nt(
        const float* __restrict__ A, const float* __restrict__ Bm,
        const float* __restrict__ bias, const float* __restrict__ res,
        float* __restrict__ C, int M, int N, int K) {
    __shared__ float As[16][68];
    __shared__ float Bs[16][68];
    int tid = threadIdx.x;
    int tx = tid & 15, ty = tid >> 4;
    int row0 = blockIdx.y * 64, col0 = blockIdx.x * 64;
    int lr = tid >> 2;          // 0..63 tile row to load
    int lk = (tid & 3) * 4;     // k sub-offset 0,4,8,12
    float acc[4][4] = {};
    for (int k0 = 0; k0 < K; k0 += 16) {
        float4 a4 = *(const float4*)(A  + (size_t)(row0 + lr) * K + k0 + lk);
        float4 b4 = *(const float4*)(Bm + (size_t)(col0 + lr) * K + k0 + lk);
        __syncthreads();   // previous iter compute done before LDS overwrite
        As[lk + 0][lr] = a4.x; As[lk + 1][lr] = a4.y;
        As[lk + 2][lr] = a4.z; As[lk + 3][lr] = a4.w;
        Bs[lk + 0][lr] = b4.x; Bs[lk + 1][lr] = b4.y;
        Bs[lk + 2][lr] = b4.z; Bs[lk + 3][lr] = b4.w;
        __syncthreads();
#pragma unroll
        for (int k = 0; k < 16; ++k) {
            float ar[4], br[4];
#pragma unroll
            for (int i = 0; i < 4; ++i) ar[i] = As[k][ty * 4 + i];
#pragma unroll
            for (int j = 0; j < 4; ++j) br[j] = Bs[k][tx * 4 + j];
#pragma unroll
            for (int i = 0; i < 4; ++i)
#pragma unroll
                for (int j = 0; j < 4; ++j)
                    acc[i][j] += ar[i] * br[j];
        }
    }
    int orow = row0 + ty * 4;
    int ocol = col0 + tx * 4;
    if (EPI == 0) {
#pragma unroll
        for (int i = 0; i < 4; ++i)
#pragma unroll
            for (int j = 0; j < 4; ++j)
                C[(size_t)(orow + i) * N + ocol + j] = acc[i][j] + bias[ocol + j];
    } else if (EPI == 1) {
#pragma unroll
        for (int i = 0; i < 4; ++i) {
            size_t doff = (size_t)win_token_to_flat(orow + i) * C_DIM;
#pragma unroll
            for (int j = 0; j < 4; ++j) {
                size_t off = doff + ocol + j;
                C[off] = res[off] + acc[i][j] + bias[ocol + j];
            }
        }
    } else if (EPI == 2) {
#pragma unroll
        for (int i = 0; i < 4; ++i)
#pragma unroll
            for (int j = 0; j < 4; ++j) {
                float val = acc[i][j] + bias[ocol + j];
                C[(size_t)(orow + i) * N + ocol + j] =
                    0.5f * val * (1.f + erff(val * 0.70710678118654752f));
            }
    } else {
#pragma unroll
        for (int i = 0; i < 4; ++i)
#pragma unroll
            for (int j = 0; j < 4; ++j) {
                size_t off = (size_t)(orow + i) * N + ocol + j;
                C[off] = res[off] + acc[i][j] + bias[ocol + j];
            }
    }
}

// Windowed MHA: one block per (window, head). N=98 tokens, hd=32.
// q/k/v staged in LDS (stride 33 -> conflict-free), one wave per row,
// rel-pos bias + shift mask computed inline, softmax via wave shuffles.
__global__ __launch_bounds__(256) void attn_kernel(
        const float* __restrict__ qkv, const float* __restrict__ rpe,
        float* __restrict__ out) {
    __shared__ float qs[98][33], ks[98][33], vs[98][33];
    __shared__ float ps[4][112];
    int blk = blockIdx.x;
    int g = blk >> 3;        // window index
    int head = blk & 7;
    int tid = threadIdx.x;

    const float* base = qkv + (size_t)g * 98 * 768 + head * 32;
    for (int i = tid; i < 98 * 32; i += 256) {
        int n = i >> 5, d = i & 31;
        size_t roff = (size_t)n * 768 + d;
        qs[n][d] = base[roff];
        ks[n][d] = base[roff + 256];
        vs[n][d] = base[roff + 512];
    }
    __syncthreads();

    int rem = g & 255;
    int tb = rem >> 6, hb = (rem >> 3) & 7, wb = rem & 7;
    int wave = tid >> 6, lane = tid & 63;
    const float scale = 0.17677669529663687f;  // 32^-0.5
    const float NEG = -1e30f;

    for (int n = wave; n < 98; n += 4) {
        int dt = n / 49, r2 = n - dt * 49, dh = r2 / 7, dw = r2 - dh * 7;
        int tn = tb * 2 + dt, hn = hb * 7 + dh, wn = wb * 7 + dw;
        int cn = ((tn < 6) ? 0 : (tn < 7) ? 1 : 2) * 9
               + ((hn < 49) ? 0 : (hn < 53) ? 1 : 2) * 3
               + ((wn < 49) ? 0 : (wn < 53) ? 1 : 2);
        float s[2];
#pragma unroll
        for (int half = 0; half < 2; ++half) {
            int m = lane + half * 64;
            if (m < 98) {
                float a = 0.f;
#pragma unroll
                for (int d = 0; d < 32; ++d) a += qs[n][d] * ks[m][d];
                int dt2 = m / 49, r3 = m - dt2 * 49, dh2 = r3 / 7, dw2 = r3 - dh2 * 7;
                int tm = tb * 2 + dt2, hm = hb * 7 + dh2, wm = wb * 7 + dw2;
                int cm = ((tm < 6) ? 0 : (tm < 7) ? 1 : 2) * 9
                       + ((hm < 49) ? 0 : (hm < 53) ? 1 : 2) * 3
                       + ((wm < 49) ? 0 : (wm < 53) ? 1 : 2);
                int idx = (dt - dt2 + 1) * 169 + (dh - dh2 + 6) * 13 + (dw - dw2 + 6);
                a = a * scale + rpe[idx * 8 + head];
                if (cm != cn) a -= 100.f;
                s[half] = a;
            } else {
                s[half] = NEG;
            }
        }
        float mx = fmaxf(s[0], s[1]);
#pragma unroll
        for (int o = 32; o > 0; o >>= 1) mx = fmaxf(mx, __shfl_xor(mx, o, 64));
        float e0 = expf(s[0] - mx);
        float e1 = (lane + 64 < 98) ? expf(s[1] - mx) : 0.f;
        float sm = e0 + e1;
#pragma unroll
        for (int o = 32; o > 0; o >>= 1) sm += __shfl_xor(sm, o, 64);
        float inv = 1.f / sm;
        ps[wave][lane] = e0 * inv;
        if (lane < 34) ps[wave][lane + 64] = e1 * inv;
        // intra-wave LDS write->read: compiler inserts lgkmcnt wait; no barrier
        if (lane < 32) {
            float o = 0.f;
            for (int m = 0; m < 98; ++m) o += ps[wave][m] * vs[m][lane];
            out[((size_t)g * 98 + n) * C_DIM + head * 32 + lane] = o;
        }
    }
}

extern "C" void kernel_launch(void* const* d_in, const int* in_sizes, int n_in,
                              void* d_out, int out_size, void* d_ws, size_t ws_size,
                              hipStream_t stream) {
    const float* x     = (const float*)d_in[0];
    const float* n1w   = (const float*)d_in[1];
    const float* n1b   = (const float*)d_in[2];
    const float* qkvw  = (const float*)d_in[3];
    const float* qkvb  = (const float*)d_in[4];
    const float* projw = (const float*)d_in[5];
    const float* projb = (const float*)d_in[6];
    const float* rpe   = (const float*)d_in[7];
    const float* n2w   = (const float*)d_in[8];
    const float* n2b   = (const float*)d_in[9];
    const float* fc1w  = (const float*)d_in[10];
    const float* fc1b  = (const float*)d_in[11];
    const float* fc2w  = (const float*)d_in[12];
    const float* fc2b  = (const float*)d_in[13];
    float* out = (float*)d_out;

    float* bufA = (float*)d_ws;            // 50176*256  (h_win -> attn_out -> h2)
    float* bufB = bufA + (size_t)TOKENS * 256;  // 50176*1024 (qkv -> fc1_out)

    // 1. LN1 + roll + window partition (gather)
    ln_kernel<true><<<TOKENS / 4, 256, 0, stream>>>(x, n1w, n1b, bufA);
    // 2. QKV projection
    gemm_nt<0><<<dim3(768 / 64, TOKENS / 64), 256, 0, stream>>>(
        bufA, qkvw, qkvb, nullptr, bufB, TOKENS, 768, 256);
    // 3. Windowed attention (bias + mask + softmax + PV), head-major output
    attn_kernel<<<NWIN * 8, 256, 0, stream>>>(bufB, rpe, bufA);
    // 4. proj + window reverse + roll back + residual -> d_out holds x1
    gemm_nt<1><<<dim3(256 / 64, TOKENS / 64), 256, 0, stream>>>(
        bufA, projw, projb, x, out, TOKENS, 256, 256);
    // 5. LN2
    ln_kernel<false><<<TOKENS / 4, 256, 0, stream>>>(out, n2w, n2b, bufA);
    // 6. FC1 + GELU
    gemm_nt<2><<<dim3(1024 / 64, TOKENS / 64), 256, 0, stream>>>(
        bufA, fc1w, fc1b, nullptr, bufB, TOKENS, 1024, 256);
    // 7. FC2 + residual (in-place on d_out)
    gemm_nt<3><<<dim3(256 / 64, TOKENS / 64), 256, 0, stream>>>(
        bufB, fc2w, fc2b, out, out, TOKENS, 256, 1024);
}

// Round 2
// 758.336 us; speedup vs baseline: 2.1443x; 2.1443x over previous
//
#include <hip/hip_runtime.h>
#include <math.h>

// Problem constants (fixed by setup_inputs)
#define TOKENS 50176   // B*T*H*W = 2*8*56*56
#define NWIN   512     // total windows = B * 256
#define C_DIM  256

typedef __attribute__((ext_vector_type(8))) short short8;
typedef __attribute__((ext_vector_type(4))) float f32x4;

// float -> bf16 with round-to-nearest-even
__device__ __forceinline__ unsigned short f2bf(float f) {
    unsigned int u = __builtin_bit_cast(unsigned int, f);
    u += 0x7fffu + ((u >> 16) & 1);
    return (unsigned short)(u >> 16);
}

// async global->LDS, 16B per lane (global_load_lds_dwordx4)
__device__ __forceinline__ void gll16(const void* g, void* l) {
    __builtin_amdgcn_global_load_lds(
        (const __attribute__((address_space(1))) unsigned int*)g,
        (__attribute__((address_space(3))) unsigned int*)l, 16, 0, 0);
}

// Map a window-ordered token index u -> flat (b,t,h,w) index.
// Serves BOTH gather (roll(-)+partition) and scatter (reverse+roll(+)).
__device__ __forceinline__ int win_token_to_flat(int u) {
    int g = u / 98;
    int n = u - g * 98;
    int bb  = g >> 8;
    int rem = g & 255;
    int tb = rem >> 6, hb = (rem >> 3) & 7, wb = rem & 7;
    int dt = n / 49;
    int r2 = n - dt * 49;
    int dh = r2 / 7, dw = r2 - dh * 7;
    int t = tb * 2 + dt, h = hb * 7 + dh, w = wb * 7 + dw;
    int ts = (t + 1) & 7;
    int hs = h + 3; if (hs >= 56) hs -= 56;
    int wsx = w + 3; if (wsx >= 56) wsx -= 56;
    return ((bb * 8 + ts) * 56 + hs) * 56 + wsx;
}

// elementwise fp32 -> bf16 (weights)
__global__ __launch_bounds__(256) void cvt_kernel(
        const float* __restrict__ src, unsigned short* __restrict__ dst, int n) {
    int i = blockIdx.x * 256 + threadIdx.x;
    if (i < n) dst[i] = f2bf(src[i]);
}

// LayerNorm over C=256, one wave per token, bf16 output.
// GATHER=true: LN1 + roll + window partition fused (gather).
template<bool GATHER>
__global__ __launch_bounds__(256) void ln_kernel(
        const float* __restrict__ x, const float* __restrict__ w,
        const float* __restrict__ b, unsigned short* __restrict__ out) {
    int token = blockIdx.x * 4 + (threadIdx.x >> 6);
    int lane  = threadIdx.x & 63;
    size_t so = GATHER ? (size_t)win_token_to_flat(token) * C_DIM
                       : (size_t)token * C_DIM;
    const float* src = x + so;
    float v[4];
    float sum = 0.f;
#pragma unroll
    for (int j = 0; j < 4; ++j) { v[j] = src[lane + 64 * j]; sum += v[j]; }
#pragma unroll
    for (int o = 32; o > 0; o >>= 1) sum += __shfl_xor(sum, o, 64);
    float mu = sum * (1.f / 256.f);
    float var = 0.f;
#pragma unroll
    for (int j = 0; j < 4; ++j) { float d = v[j] - mu; var += d * d; }
#pragma unroll
    for (int o = 32; o > 0; o >>= 1) var += __shfl_xor(var, o, 64);
    float rstd = rsqrtf(var * (1.f / 256.f) + 1e-5f);
    unsigned short* dst = out + (size_t)token * C_DIM;
#pragma unroll
    for (int j = 0; j < 4; ++j) {
        int c = lane + 64 * j;
        dst[c] = f2bf((v[j] - mu) * rstd * w[c] + b[c]);
    }
}

// bf16 MFMA GEMM: C(MxN) = A(MxK) @ B(NxK)^T, m97 structure.
// 128x128 tile, BK=32, 256 threads (4 waves), 16x16x32 bf16 MFMA,
// each wave computes 64x64 via 4x4 fragments; global_load_lds staging.
// EPI: 0 = +bias, fp32 store                    (qkv)
//      1 = +bias, scatter via map, +res, fp32   (proj)
//      2 = +bias, exact GELU, bf16 store        (fc1)
//      3 = +bias, +res in place, fp32           (fc2)
template<int EPI>
__global__ __launch_bounds__(256) void mfma_gemm(
        const unsigned short* __restrict__ A, const unsigned short* __restrict__ B,
        const float* __restrict__ bias, const float* __restrict__ res,
        void* __restrict__ Cout, int M, int N, int K) {
    __shared__ __attribute__((aligned(16))) unsigned short Asm[128 * 32];
    __shared__ __attribute__((aligned(16))) unsigned short Bsm[128 * 32];
    int tid = threadIdx.x;
    int wave = tid >> 6, lane = tid & 63;
    int row0 = blockIdx.y * 128, col0 = blockIdx.x * 128;
    int wr = (wave >> 1) * 64;      // wave's m offset in tile
    int wc = (wave & 1) * 64;       // wave's n offset in tile

    f32x4 acc[4][4] = {};

    // staging: thread t loads 8 bf16 (16B): row = t>>2 (+64), kseg = (t&3)*8
    int sr = tid >> 2;
    int sk = (tid & 3) * 8;
    const unsigned short* Ag0 = A + (size_t)(row0 + sr) * K + sk;
    const unsigned short* Ag1 = A + (size_t)(row0 + 64 + sr) * K + sk;
    const unsigned short* Bg0 = B + (size_t)(col0 + sr) * K + sk;
    const unsigned short* Bg1 = B + (size_t)(col0 + 64 + sr) * K + sk;
    unsigned short* Al = Asm + tid * 8;   // = wave base + lane*16B (contiguous)
    unsigned short* Bl = Bsm + tid * 8;

    // fragment read coords: lane holds [m = lane&15][k = (lane>>4)*8 + j]
    int fm = lane & 15, fk = (lane >> 4) * 8;

    for (int k0 = 0; k0 < K; k0 += 32) {
        __syncthreads();   // previous iter's compute done before LDS overwrite
        gll16(Ag0 + k0, Al);
        gll16(Ag1 + k0, Al + 64 * 32);
        gll16(Bg0 + k0, Bl);
        gll16(Bg1 + k0, Bl + 64 * 32);
        __syncthreads();   // drains vmcnt(0): staged data visible
        short8 af[4], bf[4];
#pragma unroll
        for (int t4 = 0; t4 < 4; ++t4) {
            af[t4] = *(const short8*)&Asm[(wr + t4 * 16 + fm) * 32 + fk];
            bf[t4] = *(const short8*)&Bsm[(wc + t4 * 16 + fm) * 32 + fk];
        }
#pragma unroll
        for (int i = 0; i < 4; ++i)
#pragma unroll
            for (int j = 0; j < 4; ++j)
                acc[i][j] = __builtin_amdgcn_mfma_f32_16x16x32_bf16(
                    af[i], bf[j], acc[i][j], 0, 0, 0);
    }

    // C/D layout: col = lane&15, row = (lane>>4)*4 + v   [m89/m91 verified]
    int crow0 = row0 + wr + (lane >> 4) * 4;
    int ccol0 = col0 + wc + (lane & 15);
    float bj[4];
#pragma unroll
    for (int j = 0; j < 4; ++j) bj[j] = bias[ccol0 + j * 16];

    if (EPI == 0) {
        float* C = (float*)Cout;
#pragma unroll
        for (int i = 0; i < 4; ++i)
#pragma unroll
            for (int v = 0; v < 4; ++v) {
                size_t base = (size_t)(crow0 + i * 16 + v) * N + ccol0;
#pragma unroll
                for (int j = 0; j < 4; ++j)
                    C[base + j * 16] = acc[i][j][v] + bj[j];
            }
    } else if (EPI == 1) {
        float* C = (float*)Cout;
#pragma unroll
        for (int i = 0; i < 4; ++i)
#pragma unroll
            for (int v = 0; v < 4; ++v) {
                int r = crow0 + i * 16 + v;
                size_t base = (size_t)win_token_to_flat(r) * C_DIM + ccol0;
#pragma unroll
                for (int j = 0; j < 4; ++j)
                    C[base + j * 16] = res[base + j * 16] + acc[i][j][v] + bj[j];
            }
    } else if (EPI == 2) {
        unsigned short* C = (unsigned short*)Cout;
#pragma unroll
        for (int i = 0; i < 4; ++i)
#pragma unroll
            for (int v = 0; v < 4; ++v) {
                size_t base = (size_t)(crow0 + i * 16 + v) * N + ccol0;
#pragma unroll
                for (int j = 0; j < 4; ++j) {
                    float val = acc[i][j][v] + bj[j];
                    C[base + j * 16] =
                        f2bf(0.5f * val * (1.f + erff(val * 0.70710678118654752f)));
                }
            }
    } else {
        float* C = (float*)Cout;
#pragma unroll
        for (int i = 0; i < 4; ++i)
#pragma unroll
            for (int v = 0; v < 4; ++v) {
                size_t base = (size_t)(crow0 + i * 16 + v) * N + ccol0;
#pragma unroll
                for (int j = 0; j < 4; ++j)
                    C[base + j * 16] = res[base + j * 16] + acc[i][j][v] + bj[j];
            }
    }
}

// Windowed MHA: one block per (window, head). N=98 tokens, hd=32.
// Unchanged from R1 except bf16 output (feeds proj MFMA GEMM).
__global__ __launch_bounds__(256) void attn_kernel(
        const float* __restrict__ qkv, const float* __restrict__ rpe,
        unsigned short* __restrict__ out) {
    __shared__ float qs[98][33], ks[98][33], vs[98][33];
    __shared__ float ps[4][112];
    int blk = blockIdx.x;
    int g = blk >> 3;
    int head = blk & 7;
    int tid = threadIdx.x;

    const float* base = qkv + (size_t)g * 98 * 768 + head * 32;
    for (int i = tid; i < 98 * 32; i += 256) {
        int n = i >> 5, d = i & 31;
        size_t roff = (size_t)n * 768 + d;
        qs[n][d] = base[roff];
        ks[n][d] = base[roff + 256];
        vs[n][d] = base[roff + 512];
    }
    __syncthreads();

    int rem = g & 255;
    int tb = rem >> 6, hb = (rem >> 3) & 7, wb = rem & 7;
    int wave = tid >> 6, lane = tid & 63;
    const float scale = 0.17677669529663687f;
    const float NEG = -1e30f;

    for (int n = wave; n < 98; n += 4) {
        int dt = n / 49, r2 = n - dt * 49, dh = r2 / 7, dw = r2 - dh * 7;
        int tn = tb * 2 + dt, hn = hb * 7 + dh, wn = wb * 7 + dw;
        int cn = ((tn < 6) ? 0 : (tn < 7) ? 1 : 2) * 9
               + ((hn < 49) ? 0 : (hn < 53) ? 1 : 2) * 3
               + ((wn < 49) ? 0 : (wn < 53) ? 1 : 2);
        float s[2];
#pragma unroll
        for (int half = 0; half < 2; ++half) {
            int m = lane + half * 64;
            if (m < 98) {
                float a = 0.f;
#pragma unroll
                for (int d = 0; d < 32; ++d) a += qs[n][d] * ks[m][d];
                int dt2 = m / 49, r3 = m - dt2 * 49, dh2 = r3 / 7, dw2 = r3 - dh2 * 7;
                int tm = tb * 2 + dt2, hm = hb * 7 + dh2, wm = wb * 7 + dw2;
                int cm = ((tm < 6) ? 0 : (tm < 7) ? 1 : 2) * 9
                       + ((hm < 49) ? 0 : (hm < 53) ? 1 : 2) * 3
                       + ((wm < 49) ? 0 : (wm < 53) ? 1 : 2);
                int idx = (dt - dt2 + 1) * 169 + (dh - dh2 + 6) * 13 + (dw - dw2 + 6);
                a = a * scale + rpe[idx * 8 + head];
                if (cm != cn) a -= 100.f;
                s[half] = a;
            } else {
                s[half] = NEG;
            }
        }
        float mx = fmaxf(s[0], s[1]);
#pragma unroll
        for (int o = 32; o > 0; o >>= 1) mx = fmaxf(mx, __shfl_xor(mx, o, 64));
        float e0 = expf(s[0] - mx);
        float e1 = (lane + 64 < 98) ? expf(s[1] - mx) : 0.f;
        float sm = e0 + e1;
#pragma unroll
        for (int o = 32; o > 0; o >>= 1) sm += __shfl_xor(sm, o, 64);
        float inv = 1.f / sm;
        ps[wave][lane] = e0 * inv;
        if (lane < 34) ps[wave][lane + 64] = e1 * inv;
        if (lane < 32) {
            float o = 0.f;
            for (int m = 0; m < 98; ++m) o += ps[wave][m] * vs[m][lane];
            out[((size_t)g * 98 + n) * C_DIM + head * 32 + lane] = f2bf(o);
        }
    }
}

extern "C" void kernel_launch(void* const* d_in, const int* in_sizes, int n_in,
                              void* d_out, int out_size, void* d_ws, size_t ws_size,
                              hipStream_t stream) {
    const float* x     = (const float*)d_in[0];
    const float* n1w   = (const float*)d_in[1];
    const float* n1b   = (const float*)d_in[2];
    const float* qkvw  = (const float*)d_in[3];
    const float* qkvb  = (const float*)d_in[4];
    const float* projw = (const float*)d_in[5];
    const float* projb = (const float*)d_in[6];
    const float* rpe   = (const float*)d_in[7];
    const float* n2w   = (const float*)d_in[8];
    const float* n2b   = (const float*)d_in[9];
    const float* fc1w  = (const float*)d_in[10];
    const float* fc1b  = (const float*)d_in[11];
    const float* fc2w  = (const float*)d_in[12];
    const float* fc2b  = (const float*)d_in[13];
    float* out = (float*)d_out;

    // workspace layout (bytes)
    char* ws = (char*)d_ws;
    unsigned short* wqkv = (unsigned short*)ws;                    // 768*256
    unsigned short* wproj = wqkv + 768 * 256;                      // 256*256
    unsigned short* wfc1 = wproj + 256 * 256;                      // 1024*256
    unsigned short* wfc2 = wfc1 + 1024 * 256;                      // 256*1024
    char* p = (char*)(wfc2 + 256 * 1024);
    unsigned short* actA = (unsigned short*)p;                     // TOKENS*256 bf16
    p += (size_t)TOKENS * 256 * 2;
    unsigned short* attnO = (unsigned short*)p;                    // TOKENS*256 bf16
    p += (size_t)TOKENS * 256 * 2;
    float* qkvf = (float*)p;                                       // TOKENS*768 fp32
    unsigned short* fc1o = (unsigned short*)p;                     // aliases qkvf (dead by then)

    // 0. weight casts to bf16
    cvt_kernel<<<(768 * 256 + 255) / 256, 256, 0, stream>>>(qkvw, wqkv, 768 * 256);
    cvt_kernel<<<(256 * 256 + 255) / 256, 256, 0, stream>>>(projw, wproj, 256 * 256);
    cvt_kernel<<<(1024 * 256 + 255) / 256, 256, 0, stream>>>(fc1w, wfc1, 1024 * 256);
    cvt_kernel<<<(256 * 1024 + 255) / 256, 256, 0, stream>>>(fc2w, wfc2, 256 * 1024);

    // 1. LN1 + roll + window partition (gather), bf16 out
    ln_kernel<true><<<TOKENS / 4, 256, 0, stream>>>(x, n1w, n1b, actA);
    // 2. QKV projection (bf16 MFMA, fp32 out)
    mfma_gemm<0><<<dim3(768 / 128, TOKENS / 128), 256, 0, stream>>>(
        actA, wqkv, qkvb, nullptr, qkvf, TOKENS, 768, 256);
    // 3. Windowed attention -> bf16
    attn_kernel<<<NWIN * 8, 256, 0, stream>>>(qkvf, rpe, attnO);
    // 4. proj + window reverse + roll back + residual -> d_out (x1, fp32)
    mfma_gemm<1><<<dim3(256 / 128, TOKENS / 128), 256, 0, stream>>>(
        attnO, wproj, projb, x, out, TOKENS, 256, 256);
    // 5. LN2 -> bf16
    ln_kernel<false><<<TOKENS / 4, 256, 0, stream>>>(out, n2w, n2b, actA);
    // 6. FC1 + GELU -> bf16 (aliases dead qkv buffer)
    mfma_gemm<2><<<dim3(1024 / 128, TOKENS / 128), 256, 0, stream>>>(
        actA, wfc1, fc1b, nullptr, fc1o, TOKENS, 1024, 256);
    // 7. FC2 + residual (in place on d_out)
    mfma_gemm<3><<<dim3(256 / 128, TOKENS / 128), 256, 0, stream>>>(
        fc1o, wfc2, fc2b, out, out, TOKENS, 256, 1024);
}

// Round 3
// 407.741 us; speedup vs baseline: 3.9880x; 1.8598x over previous
//
#include <hip/hip_runtime.h>
#include <math.h>

// Problem constants (fixed by setup_inputs)
#define TOKENS 50176   // B*T*H*W = 2*8*56*56
#define NWIN   512     // total windows = B * 256
#define C_DIM  256

typedef __attribute__((ext_vector_type(8))) short short8;
typedef __attribute__((ext_vector_type(4))) float f32x4;

// float -> bf16 with round-to-nearest-even
__device__ __forceinline__ unsigned short f2bf(float f) {
    unsigned int u = __builtin_bit_cast(unsigned int, f);
    u += 0x7fffu + ((u >> 16) & 1);
    return (unsigned short)(u >> 16);
}

// async global->LDS, 16B per lane (global_load_lds_dwordx4)
__device__ __forceinline__ void gll16(const void* g, void* l) {
    __builtin_amdgcn_global_load_lds(
        (const __attribute__((address_space(1))) unsigned int*)g,
        (__attribute__((address_space(3))) unsigned int*)l, 16, 0, 0);
}

// Map a window-ordered token index u -> flat (b,t,h,w) index.
// Serves BOTH gather (roll(-)+partition) and scatter (reverse+roll(+)).
__device__ __forceinline__ int win_token_to_flat(int u) {
    int g = u / 98;
    int n = u - g * 98;
    int bb  = g >> 8;
    int rem = g & 255;
    int tb = rem >> 6, hb = (rem >> 3) & 7, wb = rem & 7;
    int dt = n / 49;
    int r2 = n - dt * 49;
    int dh = r2 / 7, dw = r2 - dh * 7;
    int t = tb * 2 + dt, h = hb * 7 + dh, w = wb * 7 + dw;
    int ts = (t + 1) & 7;
    int hs = h + 3; if (hs >= 56) hs -= 56;
    int wsx = w + 3; if (wsx >= 56) wsx -= 56;
    return ((bb * 8 + ts) * 56 + hs) * 56 + wsx;
}

// elementwise fp32 -> bf16 (weights)
__global__ __launch_bounds__(256) void cvt_kernel(
        const float* __restrict__ src, unsigned short* __restrict__ dst, int n) {
    int i = blockIdx.x * 256 + threadIdx.x;
    if (i < n) dst[i] = f2bf(src[i]);
}

// Precompute combined rel-pos bias + shift mask tables:
// bm[cls 8][head 8][row 112][col 112] fp32. cls bits: (tb==3)<<2 | (hb==7)<<1 | (wb==7).
// col >= 98 -> -1e30 (padded K tokens), row >= 98 -> 0 (harmless pad rows).
__global__ __launch_bounds__(256) void bm_kernel(
        const float* __restrict__ rpe, float* __restrict__ bm) {
    int i = blockIdx.x * 256 + threadIdx.x;   // 8*8*112*112 = 802816 exact
    int c  = i % 112;
    int t1 = i / 112;
    int r  = t1 % 112;
    int t2 = t1 / 112;
    int head = t2 & 7;
    int cls  = t2 >> 3;
    float val;
    if (c >= 98) {
        val = -1e30f;
    } else if (r >= 98) {
        val = 0.f;
    } else {
        int dt = r / 49, rr = r - dt * 49, dh = rr / 7, dw = rr - dh * 7;
        int dt2 = c / 49, cc = c - dt2 * 49, dh2 = cc / 7, dw2 = cc - dh2 * 7;
        int rt  = (cls & 4) ? (dt  == 0 ? 1 : 2) : 0;
        int rh  = (cls & 2) ? (dh  <  4 ? 1 : 2) : 0;
        int rw  = (cls & 1) ? (dw  <  4 ? 1 : 2) : 0;
        int rt2 = (cls & 4) ? (dt2 == 0 ? 1 : 2) : 0;
        int rh2 = (cls & 2) ? (dh2 <  4 ? 1 : 2) : 0;
        int rw2 = (cls & 1) ? (dw2 <  4 ? 1 : 2) : 0;
        int reg1 = rt * 9 + rh * 3 + rw, reg2 = rt2 * 9 + rh2 * 3 + rw2;
        int idx = (dt - dt2 + 1) * 169 + (dh - dh2 + 6) * 13 + (dw - dw2 + 6);
        val = rpe[idx * 8 + head] + ((reg1 == reg2) ? 0.f : -100.f);
    }
    bm[i] = val;
}

// LayerNorm over C=256, one wave per token, bf16 output.
// GATHER=true: LN1 + roll + window partition fused (gather).
template<bool GATHER>
__global__ __launch_bounds__(256) void ln_kernel(
        const float* __restrict__ x, const float* __restrict__ w,
        const float* __restrict__ b, unsigned short* __restrict__ out) {
    int token = blockIdx.x * 4 + (threadIdx.x >> 6);
    int lane  = threadIdx.x & 63;
    size_t so = GATHER ? (size_t)win_token_to_flat(token) * C_DIM
                       : (size_t)token * C_DIM;
    const float* src = x + so;
    float v[4];
    float sum = 0.f;
#pragma unroll
    for (int j = 0; j < 4; ++j) { v[j] = src[lane + 64 * j]; sum += v[j]; }
#pragma unroll
    for (int o = 32; o > 0; o >>= 1) sum += __shfl_xor(sum, o, 64);
    float mu = sum * (1.f / 256.f);
    float var = 0.f;
#pragma unroll
    for (int j = 0; j < 4; ++j) { float d = v[j] - mu; var += d * d; }
#pragma unroll
    for (int o = 32; o > 0; o >>= 1) var += __shfl_xor(var, o, 64);
    float rstd = rsqrtf(var * (1.f / 256.f) + 1e-5f);
    unsigned short* dst = out + (size_t)token * C_DIM;
#pragma unroll
    for (int j = 0; j < 4; ++j) {
        int c = lane + 64 * j;
        dst[c] = f2bf((v[j] - mu) * rstd * w[c] + b[c]);
    }
}

// bf16 MFMA GEMM: C(MxN) = A(MxK) @ B(NxK)^T, m97 structure.
// EPI: 0 = +bias, *scale on Q cols (blockIdx.x<2), bf16 store   (qkv)
//      1 = +bias, scatter via map, +res, fp32                   (proj)
//      2 = +bias, exact GELU, bf16 store                        (fc1)
//      3 = +bias, +res in place, fp32                           (fc2)
template<int EPI>
__global__ __launch_bounds__(256) void mfma_gemm(
        const unsigned short* __restrict__ A, const unsigned short* __restrict__ B,
        const float* __restrict__ bias, const float* __restrict__ res,
        void* __restrict__ Cout, int M, int N, int K) {
    __shared__ __attribute__((aligned(16))) unsigned short Asm[128 * 32];
    __shared__ __attribute__((aligned(16))) unsigned short Bsm[128 * 32];
    int tid = threadIdx.x;
    int wave = tid >> 6, lane = tid & 63;
    int row0 = blockIdx.y * 128, col0 = blockIdx.x * 128;
    int wr = (wave >> 1) * 64;
    int wc = (wave & 1) * 64;

    f32x4 acc[4][4] = {};

    int sr = tid >> 2;
    int sk = (tid & 3) * 8;
    const unsigned short* Ag0 = A + (size_t)(row0 + sr) * K + sk;
    const unsigned short* Ag1 = A + (size_t)(row0 + 64 + sr) * K + sk;
    const unsigned short* Bg0 = B + (size_t)(col0 + sr) * K + sk;
    const unsigned short* Bg1 = B + (size_t)(col0 + 64 + sr) * K + sk;
    unsigned short* Al = Asm + tid * 8;
    unsigned short* Bl = Bsm + tid * 8;

    int fm = lane & 15, fk = (lane >> 4) * 8;

    for (int k0 = 0; k0 < K; k0 += 32) {
        __syncthreads();
        gll16(Ag0 + k0, Al);
        gll16(Ag1 + k0, Al + 64 * 32);
        gll16(Bg0 + k0, Bl);
        gll16(Bg1 + k0, Bl + 64 * 32);
        __syncthreads();
        short8 af[4], bf[4];
#pragma unroll
        for (int t4 = 0; t4 < 4; ++t4) {
            af[t4] = *(const short8*)&Asm[(wr + t4 * 16 + fm) * 32 + fk];
            bf[t4] = *(const short8*)&Bsm[(wc + t4 * 16 + fm) * 32 + fk];
        }
#pragma unroll
        for (int i = 0; i < 4; ++i)
#pragma unroll
            for (int j = 0; j < 4; ++j)
                acc[i][j] = __builtin_amdgcn_mfma_f32_16x16x32_bf16(
                    af[i], bf[j], acc[i][j], 0, 0, 0);
    }

    int crow0 = row0 + wr + (lane >> 4) * 4;
    int ccol0 = col0 + wc + (lane & 15);
    float bj[4];
#pragma unroll
    for (int j = 0; j < 4; ++j) bj[j] = bias[ccol0 + j * 16];

    if (EPI == 0) {
        unsigned short* C = (unsigned short*)Cout;
        float mul = (col0 < 256) ? 0.17677669529663687f : 1.f;  // scale Q
#pragma unroll
        for (int i = 0; i < 4; ++i)
#pragma unroll
            for (int v = 0; v < 4; ++v) {
                size_t base = (size_t)(crow0 + i * 16 + v) * N + ccol0;
#pragma unroll
                for (int j = 0; j < 4; ++j)
                    C[base + j * 16] = f2bf((acc[i][j][v] + bj[j]) * mul);
            }
    } else if (EPI == 1) {
        float* C = (float*)Cout;
#pragma unroll
        for (int i = 0; i < 4; ++i)
#pragma unroll
            for (int v = 0; v < 4; ++v) {
                int r = crow0 + i * 16 + v;
                size_t base = (size_t)win_token_to_flat(r) * C_DIM + ccol0;
#pragma unroll
                for (int j = 0; j < 4; ++j)
                    C[base + j * 16] = res[base + j * 16] + acc[i][j][v] + bj[j];
            }
    } else if (EPI == 2) {
        unsigned short* C = (unsigned short*)Cout;
#pragma unroll
        for (int i = 0; i < 4; ++i)
#pragma unroll
            for (int v = 0; v < 4; ++v) {
                size_t base = (size_t)(crow0 + i * 16 + v) * N + ccol0;
#pragma unroll
                for (int j = 0; j < 4; ++j) {
                    float val = acc[i][j][v] + bj[j];
                    C[base + j * 16] =
                        f2bf(0.5f * val * (1.f + erff(val * 0.70710678118654752f)));
                }
            }
    } else {
        float* C = (float*)Cout;
#pragma unroll
        for (int i = 0; i < 4; ++i)
#pragma unroll
            for (int v = 0; v < 4; ++v) {
                size_t base = (size_t)(crow0 + i * 16 + v) * N + ccol0;
#pragma unroll
                for (int j = 0; j < 4; ++j)
                    C[base + j * 16] = res[base + j * 16] + acc[i][j][v] + bj[j];
            }
    }
}

// MFMA windowed attention: one block per (window, head), 4 waves.
// N=98 padded to 112 (7 row-strips of 16). Per strip (owned by one wave):
//   S = Q K^T (7 MFMA, A/B frags direct from global, row-clamped)
//   + bm table, row softmax (16-lane shfl_xor), P -> LDS (C->A layout),
//   O = P V via 8 MFMA against LDS-transposed V, *1/rowsum at store.
// qkv is bf16, Q pre-scaled by 32^-0.5 in the qkv GEMM epilogue.
__global__ __launch_bounds__(256) void attn_mfma_kernel(
        const unsigned short* __restrict__ qkv, const float* __restrict__ bm,
        unsigned short* __restrict__ out) {
    __shared__ __attribute__((aligned(16))) unsigned short Vt[32][136];
    __shared__ __attribute__((aligned(16))) unsigned short Pw[4][16][136];
    int blk = blockIdx.x;
    int g = blk >> 3, head = blk & 7;
    int tid = threadIdx.x, wave = tid >> 6, lane = tid & 63;

    // zero Vt token-pad cols [98,128) (P pad cols are exact 0, need finite V there)
    for (int i = tid; i < 32 * 30; i += 256) {
        int d = i / 30, c = 98 + (i - d * 30);
        Vt[d][c] = 0;
    }
    // stage V_h transposed: Vt[d][token], coalesced global reads
    const unsigned short* vbase = qkv + (size_t)g * 98 * 768 + 512 + head * 32;
    for (int i = tid; i < 98 * 16; i += 256) {
        int n = i >> 4, dp = i & 15;
        unsigned int val = *(const unsigned int*)(vbase + (size_t)n * 768 + dp * 2);
        Vt[dp * 2][n]     = (unsigned short)val;
        Vt[dp * 2 + 1][n] = (unsigned short)(val >> 16);
    }
    // zero per-wave P k-pad cols [112,128) (read by last PV k-step)
    {
        int m = lane >> 2, c = 112 + (lane & 3) * 4;
        *(unsigned long long*)&Pw[wave][m][c] = 0ULL;
    }
    __syncthreads();

    const unsigned short* qbase = qkv + (size_t)g * 98 * 768 + head * 32;
    const unsigned short* kbase = qbase + 256;
    int rem = g & 255;
    int cls = (((rem >> 6) == 3) << 2) | (((((rem >> 3) & 7)) == 7) << 1) | ((rem & 7) == 7);
    const float* bmh = bm + (size_t)(cls * 8 + head) * 112 * 112;

    int fm = lane & 15, fq = lane >> 4;
    int fk = fq * 8;
    unsigned short* obase = out + (size_t)g * 98 * 256 + head * 32;

    for (int s = wave; s < 7; s += 4) {
        int m0 = s * 16;
        int arow = m0 + fm; if (arow > 97) arow = 97;   // clamp pad rows (finite garbage)
        short8 af = *(const short8*)(qbase + (size_t)arow * 768 + fk);
        f32x4 S[7];
        f32x4 z = {0.f, 0.f, 0.f, 0.f};
#pragma unroll
        for (int j = 0; j < 7; ++j) {
            int krow = j * 16 + fm; if (krow > 97) krow = 97;
            short8 kf = *(const short8*)(kbase + (size_t)krow * 768 + fk);
            S[j] = __builtin_amdgcn_mfma_f32_16x16x32_bf16(af, kf, z, 0, 0, 0);
        }
        // + bias/mask table (pad cols get -1e30 -> exp 0)
        const float* bmrow = bmh + (m0 + fq * 4) * 112 + fm;
#pragma unroll
        for (int j = 0; j < 7; ++j)
#pragma unroll
            for (int v = 0; v < 4; ++v)
                S[j][v] += bmrow[v * 112 + j * 16];
        // row softmax: rows live in 16-lane col groups (lane&15), 4 rows/lane (v)
        float inv[4];
#pragma unroll
        for (int v = 0; v < 4; ++v) {
            float m_ = S[0][v];
#pragma unroll
            for (int j = 1; j < 7; ++j) m_ = fmaxf(m_, S[j][v]);
#pragma unroll
            for (int o = 1; o < 16; o <<= 1) m_ = fmaxf(m_, __shfl_xor(m_, o, 64));
            float t = 0.f;
#pragma unroll
            for (int j = 0; j < 7; ++j) { S[j][v] = __expf(S[j][v] - m_); t += S[j][v]; }
#pragma unroll
            for (int o = 1; o < 16; o <<= 1) t += __shfl_xor(t, o, 64);
            inv[v] = 1.f / t;   // applied at output store (PV is linear)
        }
        // P: C-layout -> A-layout via per-wave LDS (same-wave DS ordering, no barrier)
#pragma unroll
        for (int j = 0; j < 7; ++j)
#pragma unroll
            for (int v = 0; v < 4; ++v)
                Pw[wave][fq * 4 + v][j * 16 + fm] = f2bf(S[j][v]);
        // O = P @ V
        f32x4 O0 = {0.f, 0.f, 0.f, 0.f}, O1 = {0.f, 0.f, 0.f, 0.f};
#pragma unroll
        for (int ks = 0; ks < 4; ++ks) {
            short8 pf = *(const short8*)&Pw[wave][fm][ks * 32 + fk];
            short8 v0 = *(const short8*)&Vt[fm][ks * 32 + fk];
            short8 v1 = *(const short8*)&Vt[16 + fm][ks * 32 + fk];
            O0 = __builtin_amdgcn_mfma_f32_16x16x32_bf16(pf, v0, O0, 0, 0, 0);
            O1 = __builtin_amdgcn_mfma_f32_16x16x32_bf16(pf, v1, O1, 0, 0, 0);
        }
#pragma unroll
        for (int v = 0; v < 4; ++v) {
            int row = m0 + fq * 4 + v;
            if (row < 98) {
                obase[(size_t)row * 256 + fm]      = f2bf(O0[v] * inv[v]);
                obase[(size_t)row * 256 + 16 + fm] = f2bf(O1[v] * inv[v]);
            }
        }
    }
}

extern "C" void kernel_launch(void* const* d_in, const int* in_sizes, int n_in,
                              void* d_out, int out_size, void* d_ws, size_t ws_size,
                              hipStream_t stream) {
    const float* x     = (const float*)d_in[0];
    const float* n1w   = (const float*)d_in[1];
    const float* n1b   = (const float*)d_in[2];
    const float* qkvw  = (const float*)d_in[3];
    const float* qkvb  = (const float*)d_in[4];
    const float* projw = (const float*)d_in[5];
    const float* projb = (const float*)d_in[6];
    const float* rpe   = (const float*)d_in[7];
    const float* n2w   = (const float*)d_in[8];
    const float* n2b   = (const float*)d_in[9];
    const float* fc1w  = (const float*)d_in[10];
    const float* fc1b  = (const float*)d_in[11];
    const float* fc2w  = (const float*)d_in[12];
    const float* fc2b  = (const float*)d_in[13];
    float* out = (float*)d_out;

    // workspace layout
    unsigned short* wqkv  = (unsigned short*)d_ws;            // 768*256 bf16
    unsigned short* wproj = wqkv + 768 * 256;                 // 256*256
    unsigned short* wfc1  = wproj + 256 * 256;                // 1024*256
    unsigned short* wfc2  = wfc1 + 1024 * 256;                // 256*1024
    float* bm = (float*)(wfc2 + 256 * 1024);                  // 8*8*112*112 fp32
    unsigned short* actA  = (unsigned short*)(bm + 8 * 8 * 112 * 112); // TOKENS*256 bf16
    unsigned short* attnO = actA + (size_t)TOKENS * 256;      // TOKENS*256 bf16
    unsigned short* qkv_bf = attnO + (size_t)TOKENS * 256;    // TOKENS*768 bf16
    unsigned short* fc1o = qkv_bf;                            // TOKENS*1024 bf16 (aliases dead qkv)

    // 0. bias/mask tables + weight casts
    bm_kernel<<<8 * 8 * 112 * 112 / 256, 256, 0, stream>>>(rpe, bm);
    cvt_kernel<<<(768 * 256 + 255) / 256, 256, 0, stream>>>(qkvw, wqkv, 768 * 256);
    cvt_kernel<<<(256 * 256 + 255) / 256, 256, 0, stream>>>(projw, wproj, 256 * 256);
    cvt_kernel<<<(1024 * 256 + 255) / 256, 256, 0, stream>>>(fc1w, wfc1, 1024 * 256);
    cvt_kernel<<<(256 * 1024 + 255) / 256, 256, 0, stream>>>(fc2w, wfc2, 256 * 1024);

    // 1. LN1 + roll + window partition (gather), bf16 out
    ln_kernel<true><<<TOKENS / 4, 256, 0, stream>>>(x, n1w, n1b, actA);
    // 2. QKV projection -> bf16, Q pre-scaled
    mfma_gemm<0><<<dim3(768 / 128, TOKENS / 128), 256, 0, stream>>>(
        actA, wqkv, qkvb, nullptr, qkv_bf, TOKENS, 768, 256);
    // 3. MFMA windowed attention -> bf16
    attn_mfma_kernel<<<NWIN * 8, 256, 0, stream>>>(qkv_bf, bm, attnO);
    // 4. proj + window reverse + roll back + residual -> d_out (x1, fp32)
    mfma_gemm<1><<<dim3(256 / 128, TOKENS / 128), 256, 0, stream>>>(
        attnO, wproj, projb, x, out, TOKENS, 256, 256);
    // 5. LN2 -> bf16
    ln_kernel<false><<<TOKENS / 4, 256, 0, stream>>>(out, n2w, n2b, actA);
    // 6. FC1 + GELU -> bf16 (aliases dead qkv buffer)
    mfma_gemm<2><<<dim3(1024 / 128, TOKENS / 128), 256, 0, stream>>>(
        actA, wfc1, fc1b, nullptr, fc1o, TOKENS, 1024, 256);
    // 7. FC2 + residual (in place on d_out)
    mfma_gemm<3><<<dim3(256 / 128, TOKENS / 128), 256, 0, stream>>>(
        fc1o, wfc2, fc2b, out, out, TOKENS, 256, 1024);
}